// Round 1
// baseline (1013.498 us; speedup 1.0000x reference)
//
#include <hip/hip_runtime.h>

typedef __bf16 bf16;
typedef __bf16 bf16x8 __attribute__((ext_vector_type(8)));
typedef __bf16 bf16x4 __attribute__((ext_vector_type(4)));
typedef float  f32x4  __attribute__((ext_vector_type(4)));

// ---------------------------------------------------------------------------
// f32 -> bf16 convert, 4-wide
// ---------------------------------------------------------------------------
__global__ void f2b_kernel(const float* __restrict__ src, bf16* __restrict__ dst, int n4) {
    int i = blockIdx.x * 256 + threadIdx.x;
    if (i >= n4) return;
    float4 v = ((const float4*)src)[i];
    bf16x4 o = { (bf16)v.x, (bf16)v.y, (bf16)v.z, (bf16)v.w };
    ((bf16x4*)dst)[i] = o;
}

// ---------------------------------------------------------------------------
// Swizzle fp32 W (taps, cin, cout) into bf16 MFMA-B-fragment order:
//   Wf[tap][s][nt][lane][j] = W[tap][s*32 + (lane>>4)*8 + j][nt*16 + (lane&15)]
// so a B-fragment load is one contiguous 16B read per lane.
// ---------------------------------------------------------------------------
__global__ void swz_kernel(const float* __restrict__ W, bf16* __restrict__ Wf,
                           int cin, int cout, int total) {
    int e = blockIdx.x * 256 + threadIdx.x;
    if (e >= total) return;
    int per_tap = cin * cout;
    int tap = e / per_tap;
    int t2  = e - tap * per_tap;
    int ntc = cout >> 4;               // number of 16-col tiles
    int s   = t2 / (ntc * 512);        // K-step of 32
    int r3  = t2 - s * (ntc * 512);
    int nt  = r3 >> 9;
    int L   = (r3 & 511) >> 3;
    int j   = r3 & 7;
    int k   = s * 32 + (L >> 4) * 8 + j;
    int col = nt * 16 + (L & 15);
    Wf[e] = (bf16)W[((size_t)tap * cin + k) * cout + col];
}

// ---------------------------------------------------------------------------
// One fused layer: Y = relu( (sum_k gather_k(X) @ W[k]) * sc + sh )
// TAPS==1 -> dense GEMM (identity gather). Output bf16 (Y) or fp32 (Yf).
// Block: 256 threads (4 waves), tile 64 rows x COUT cols, 16x16x32 bf16 MFMA.
// ---------------------------------------------------------------------------
template<int CIN, int COUT, int TAPS>
__global__ __launch_bounds__(256) void layer_kernel(
    const bf16* __restrict__ X,
    const bf16* __restrict__ Wf,
    const int*  __restrict__ nbr,     // (TAPS, n) or nullptr when TAPS==1
    const float* __restrict__ sc, const float* __restrict__ sh,
    bf16* __restrict__ Y, float* __restrict__ Yf,
    int ystride, int yoff, int n)
{
    constexpr int NT  = COUT / 16;        // 16-col tiles
    constexpr int KS  = CIN / 32;         // K-steps per tap
    constexpr int AST = CIN + 8;          // padded LDS row stride (breaks bank aliasing)
    constexpr int WR  = (COUT >= 64) ? 2 : 1;   // row-tiles per wave
    constexpr int WC  = (COUT == 128) ? 4 : 2;  // col-tiles per wave
    constexpr int RGRP = 4 / WR;          // wave row-groups (x col-groups == 4 waves)

    __shared__ __align__(16) bf16 As[64 * AST];
    __shared__ __align__(16) bf16 Bs[CIN * COUT];

    const int tid  = threadIdx.x;
    const int base = blockIdx.x * 64;
    const int lane = tid & 63;
    const int wv   = tid >> 6;
    const int wrow = wv % RGRP;
    const int wcol = wv / RGRP;
    const int m16  = lane & 15;
    const int quad = lane >> 4;

    f32x4 acc[WR][WC];
#pragma unroll
    for (int r = 0; r < WR; ++r)
#pragma unroll
        for (int c = 0; c < WC; ++c) acc[r][c] = (f32x4){0.f, 0.f, 0.f, 0.f};

    for (int tap = 0; tap < TAPS; ++tap) {
        __syncthreads();
        // ---- stage A: 64 gathered rows x CIN (zeros for missing neighbors) ----
        constexpr int CH = CIN / 8;   // 16B chunks per row
#pragma unroll
        for (int e = tid; e < 64 * CH; e += 256) {
            int r = e / CH, c = e - r * CH;
            int idx = (TAPS == 1) ? (base + r) : nbr[tap * n + base + r];
            float4 val = {0.f, 0.f, 0.f, 0.f};
            if (idx >= 0) val = *(const float4*)(X + (size_t)idx * CIN + c * 8);
            *(float4*)(&As[r * AST + c * 8]) = val;
        }
        // ---- stage B: pre-swizzled tap slice, straight copy ----
        const float4* wsrc = (const float4*)(Wf + (size_t)tap * CIN * COUT);
#pragma unroll
        for (int e = tid; e < CIN * COUT / 8; e += 256)
            *(float4*)(&Bs[e * 8]) = wsrc[e];
        __syncthreads();

        // ---- MFMA K-loop ----
#pragma unroll
        for (int s = 0; s < KS; ++s) {
            bf16x8 a[WR], b[WC];
#pragma unroll
            for (int r = 0; r < WR; ++r) {
                int row = (wrow * WR + r) * 16 + m16;
                a[r] = *(const bf16x8*)(&As[row * AST + s * 32 + quad * 8]);
            }
#pragma unroll
            for (int c = 0; c < WC; ++c) {
                int nt = wcol * WC + c;
                b[c] = *(const bf16x8*)(&Bs[(s * NT + nt) * 512 + lane * 8]);
            }
#pragma unroll
            for (int r = 0; r < WR; ++r)
#pragma unroll
                for (int c = 0; c < WC; ++c)
                    acc[r][c] = __builtin_amdgcn_mfma_f32_16x16x32_bf16(a[r], b[c], acc[r][c], 0, 0, 0);
        }
    }

    // ---- epilogue: BN (folded) + ReLU; C/D layout col=lane&15, row=quad*4+i ----
#pragma unroll
    for (int c = 0; c < WC; ++c) {
        int col = (wcol * WC + c) * 16 + m16;
        float scale = sc[col], shift = sh[col];
#pragma unroll
        for (int r = 0; r < WR; ++r) {
            int row0 = base + (wrow * WR + r) * 16 + quad * 4;
#pragma unroll
            for (int i = 0; i < 4; ++i) {
                float v = acc[r][c][i] * scale + shift;
                v = v > 0.f ? v : 0.f;
                size_t off = (size_t)(row0 + i) * ystride + yoff + col;
                if (Yf) Yf[off] = v;
                else    Y[off] = (bf16)v;
            }
        }
    }
}

// ---------------------------------------------------------------------------
// z[:, 64:96] = sanitize(y2[align_idx])  (features_at_coordinates + concat)
// ---------------------------------------------------------------------------
__global__ void concat_kernel(const bf16* __restrict__ y2, const int* __restrict__ align,
                              bf16* __restrict__ z, int n) {
    int e = blockIdx.x * 256 + threadIdx.x;   // over n*32
    if (e >= n * 32) return;
    int i = e >> 5, c = e & 31;
    int a = align[i];
    float v = (float)y2[(size_t)a * 32 + c];
    unsigned u = __builtin_bit_cast(unsigned, v);
    if ((u & 0x7f800000u) == 0x7f800000u) v = 0.f;   // NaN/Inf -> 0
    z[(size_t)i * 96 + 64 + c] = (bf16)v;
}

// ---------------------------------------------------------------------------
extern "C" void kernel_launch(void* const* d_in, const int* in_sizes, int n_in,
                              void* d_out, int out_size, void* d_ws, size_t ws_size,
                              hipStream_t stream) {
    const float* feat3d = (const float*)d_in[0];
    const float* feat2d = (const float*)d_in[1];
    const float* Wsrc[11];
    for (int i = 0; i < 11; ++i) Wsrc[i] = (const float*)d_in[2 + i];
    const float* bn[22];
    for (int i = 0; i < 22; ++i) bn[i] = (const float*)d_in[13 + i];
    const int* nbr   = (const int*)d_in[35];
    const int* align = (const int*)d_in[36];
    float* out = (float*)d_out;

    const int n = in_sizes[0] / 96;   // 80000, divisible by 64

    // workspace layout
    char* ws = (char*)d_ws;
    size_t off = 0;
    auto alloc = [&](size_t bytes) -> void* {
        void* p = ws + off;
        off = (off + bytes + 255) & ~(size_t)255;
        return p;
    };
    bf16* F3 = (bf16*)alloc((size_t)n * 96 * 2);
    bf16* F2 = (bf16*)alloc((size_t)n * 256 * 2);
    static const int wt_taps[11] = {27, 1, 27, 1, 27, 1, 27, 1, 27, 1, 1};
    static const int wt_cin[11]  = {96, 64, 64, 64, 256, 64, 64, 32, 96, 128, 128};
    static const int wt_cout[11] = {64, 64, 64, 64, 64, 64, 32, 32, 128, 128, 128};
    bf16* Wf[11];
    for (int i = 0; i < 11; ++i)
        Wf[i] = (bf16*)alloc((size_t)wt_taps[i] * wt_cin[i] * wt_cout[i] * 2);
    bf16* tA = (bf16*)alloc((size_t)n * 64 * 2);
    bf16* tB = (bf16*)alloc((size_t)n * 64 * 2);
    bf16* y2 = (bf16*)alloc((size_t)n * 32 * 2);
    bf16* z  = (bf16*)alloc((size_t)n * 96 * 2);
    bf16* w1 = (bf16*)alloc((size_t)n * 128 * 2);
    bf16* w2 = (bf16*)alloc((size_t)n * 128 * 2);

    // ---- prep: converts + weight swizzles ----
    f2b_kernel<<<(n * 96 / 4 + 255) / 256, 256, 0, stream>>>(feat3d, F3, n * 96 / 4);
    f2b_kernel<<<(n * 256 / 4 + 255) / 256, 256, 0, stream>>>(feat2d, F2, n * 256 / 4);
    for (int i = 0; i < 11; ++i) {
        int total = wt_taps[i] * wt_cin[i] * wt_cout[i];
        swz_kernel<<<(total + 255) / 256, 256, 0, stream>>>(Wsrc[i], Wf[i], wt_cin[i], wt_cout[i], total);
    }

    const int GB = n / 64;   // 1250 blocks

    // ---- 3D branch: 96 -> 64 ----
    layer_kernel<96, 64, 27><<<GB, 256, 0, stream>>>(F3, Wf[0], nbr, bn[0], bn[1], tA, nullptr, 64, 0, n);
    layer_kernel<64, 64, 1 ><<<GB, 256, 0, stream>>>(tA, Wf[1], nullptr, bn[2], bn[3], tB, nullptr, 64, 0, n);
    layer_kernel<64, 64, 27><<<GB, 256, 0, stream>>>(tB, Wf[2], nbr, bn[4], bn[5], tA, nullptr, 64, 0, n);
    layer_kernel<64, 64, 1 ><<<GB, 256, 0, stream>>>(tA, Wf[3], nullptr, bn[6], bn[7], z, nullptr, 96, 0, n);   // x3 -> z[:,0:64]

    // ---- 2D branch: 256 -> 32 ----
    layer_kernel<256, 64, 27><<<GB, 256, 0, stream>>>(F2, Wf[4], nbr, bn[8], bn[9], tA, nullptr, 64, 0, n);
    layer_kernel<64, 64, 1  ><<<GB, 256, 0, stream>>>(tA, Wf[5], nullptr, bn[10], bn[11], tB, nullptr, 64, 0, n);
    layer_kernel<64, 32, 27 ><<<GB, 256, 0, stream>>>(tB, Wf[6], nbr, bn[12], bn[13], tA, nullptr, 32, 0, n);
    layer_kernel<32, 32, 1  ><<<GB, 256, 0, stream>>>(tA, Wf[7], nullptr, bn[14], bn[15], y2, nullptr, 32, 0, n);

    // ---- align gather + concat into z[:,64:96] ----
    concat_kernel<<<(n * 32 + 255) / 256, 256, 0, stream>>>(y2, align, z, n);

    // ---- fusion: 96 -> 128 -> 128 -> 128 ----
    layer_kernel<96, 128, 27><<<GB, 256, 0, stream>>>(z, Wf[8], nbr, bn[16], bn[17], w1, nullptr, 128, 0, n);
    layer_kernel<128, 128, 1><<<GB, 256, 0, stream>>>(w1, Wf[9], nullptr, bn[18], bn[19], w2, nullptr, 128, 0, n);
    layer_kernel<128, 128, 1><<<GB, 256, 0, stream>>>(w2, Wf[10], nullptr, bn[20], bn[21], nullptr, out, 128, 0, n);
}

// Round 2
// 827.807 us; speedup vs baseline: 1.2243x; 1.2243x over previous
//
#include <hip/hip_runtime.h>

typedef __bf16 bf16;
typedef __bf16 bf16x8 __attribute__((ext_vector_type(8)));
typedef __bf16 bf16x4 __attribute__((ext_vector_type(4)));
typedef float  f32x4  __attribute__((ext_vector_type(4)));

// ---------------------------------------------------------------------------
// f32 -> bf16 convert, 4-wide
// ---------------------------------------------------------------------------
__global__ void f2b_kernel(const float* __restrict__ src, bf16* __restrict__ dst, int n4) {
    int i = blockIdx.x * 256 + threadIdx.x;
    if (i >= n4) return;
    float4 v = ((const float4*)src)[i];
    bf16x4 o = { (bf16)v.x, (bf16)v.y, (bf16)v.z, (bf16)v.w };
    ((bf16x4*)dst)[i] = o;
}

// ---------------------------------------------------------------------------
// Swizzle fp32 W (taps, cin, cout) into bf16 MFMA-B-fragment order:
//   Wf[tap][s][nt][lane][j] = W[tap][s*32 + (lane>>4)*8 + j][nt*16 + (lane&15)]
// so a B-fragment load is one contiguous 16B read per lane.
// ---------------------------------------------------------------------------
__global__ void swz_kernel(const float* __restrict__ W, bf16* __restrict__ Wf,
                           int cin, int cout, int total) {
    int e = blockIdx.x * 256 + threadIdx.x;
    if (e >= total) return;
    int per_tap = cin * cout;
    int tap = e / per_tap;
    int t2  = e - tap * per_tap;
    int ntc = cout >> 4;               // number of 16-col tiles
    int s   = t2 / (ntc * 512);        // K-step of 32
    int r3  = t2 - s * (ntc * 512);
    int nt  = r3 >> 9;
    int L   = (r3 & 511) >> 3;
    int j   = r3 & 7;
    int k   = s * 32 + (L >> 4) * 8 + j;
    int col = nt * 16 + (L & 15);
    Wf[e] = (bf16)W[((size_t)tap * cin + k) * cout + col];
}

// ---------------------------------------------------------------------------
// One fused layer: Y = relu( (sum_k gather_k(X) @ W[k]) * sc + sh )
// TAPS==1 -> dense GEMM (identity gather). Output bf16 (Y) or fp32 (Yf).
// Block: 256 threads (4 waves), tile 64 rows x COUT cols, 16x16x32 bf16 MFMA.
// A-gather double-buffered in LDS (1 barrier/tap); B-fragments loaded
// directly global->VGPR (W is L2-resident, coalesced 16B/lane); nbr indices
// preloaded to LDS once per block.
// ---------------------------------------------------------------------------
template<int CIN, int COUT, int TAPS>
__global__ __launch_bounds__(256) void layer_kernel(
    const bf16* __restrict__ X,
    const bf16* __restrict__ Wf,
    const int*  __restrict__ nbr,     // (TAPS, n) or nullptr when TAPS==1
    const float* __restrict__ sc, const float* __restrict__ sh,
    bf16* __restrict__ Y, float* __restrict__ Yf,
    int ystride, int yoff, int n)
{
    constexpr int NT  = COUT / 16;        // 16-col tiles
    constexpr int KS  = CIN / 32;         // K-steps per tap
    constexpr int AST = CIN + 8;          // padded LDS row stride (2-way max on reads = free)
    constexpr int WR  = (COUT >= 64) ? 2 : 1;   // row-tiles per wave
    constexpr int WC  = (COUT == 128) ? 4 : 2;  // col-tiles per wave
    constexpr int RGRP = 4 / WR;          // wave row-groups (x col-groups == 4 waves)
    constexpr int NBUF = (TAPS > 1) ? 2 : 1;
    constexpr int IDXN = (TAPS > 1) ? TAPS * 64 : 64;

    __shared__ __align__(16) bf16 As[NBUF][64 * AST];
    __shared__ int idxs[IDXN];

    const int tid  = threadIdx.x;
    const int base = blockIdx.x * 64;
    const int lane = tid & 63;
    const int wv   = tid >> 6;
    const int wrow = wv % RGRP;
    const int wcol = wv / RGRP;
    const int m16  = lane & 15;
    const int quad = lane >> 4;

    // ---- preload all tap indices for this block ----
    if (TAPS > 1) {
        for (int e = tid; e < TAPS * 64; e += 256)
            idxs[e] = nbr[(e >> 6) * n + base + (e & 63)];
        __syncthreads();
    }

    auto stage = [&](int t, int buf) {
        constexpr int CH = CIN / 8;   // 16B chunks per row
#pragma unroll
        for (int e = tid; e < 64 * CH; e += 256) {
            int r = e / CH, c = e - r * CH;
            int idx = (TAPS == 1) ? (base + r) : idxs[t * 64 + r];
            float4 val = {0.f, 0.f, 0.f, 0.f};
            if (idx >= 0) val = *(const float4*)(X + (size_t)idx * CIN + c * 8);
            *(float4*)(&As[buf][r * AST + c * 8]) = val;
        }
    };

    f32x4 acc[WR][WC];
#pragma unroll
    for (int r = 0; r < WR; ++r)
#pragma unroll
        for (int c = 0; c < WC; ++c) acc[r][c] = (f32x4){0.f, 0.f, 0.f, 0.f};

    stage(0, 0);
    int buf = 0;

    for (int t = 0; t < TAPS; ++t) {
        __syncthreads();               // A(t) staged

        // B-fragments for tap t: straight from global (issue these first so
        // their vmcnt drains before the staging loads below)
        bf16x8 b[KS][WC];
        const bf16* wt = Wf + (size_t)t * (CIN * COUT);
#pragma unroll
        for (int s = 0; s < KS; ++s)
#pragma unroll
            for (int c = 0; c < WC; ++c)
                b[s][c] = *(const bf16x8*)(wt + (s * NT + wcol * WC + c) * 512 + lane * 8);

        // prefetch A(t+1) into the other buffer; overlaps compute below
        if (TAPS > 1 && t + 1 < TAPS) stage(t + 1, buf ^ 1);

        // ---- MFMA K-loop on tap t ----
#pragma unroll
        for (int s = 0; s < KS; ++s) {
            bf16x8 a[WR];
#pragma unroll
            for (int r = 0; r < WR; ++r) {
                int row = (wrow * WR + r) * 16 + m16;
                a[r] = *(const bf16x8*)(&As[buf][row * AST + s * 32 + quad * 8]);
            }
#pragma unroll
            for (int r = 0; r < WR; ++r)
#pragma unroll
                for (int c = 0; c < WC; ++c)
                    acc[r][c] = __builtin_amdgcn_mfma_f32_16x16x32_bf16(a[r], b[s][c], acc[r][c], 0, 0, 0);
        }
        buf ^= (NBUF - 1);
    }

    // ---- epilogue: BN (folded) + ReLU; C/D layout col=lane&15, row=quad*4+i ----
#pragma unroll
    for (int c = 0; c < WC; ++c) {
        int col = (wcol * WC + c) * 16 + m16;
        float scale = sc[col], shift = sh[col];
#pragma unroll
        for (int r = 0; r < WR; ++r) {
            int row0 = base + (wrow * WR + r) * 16 + quad * 4;
#pragma unroll
            for (int i = 0; i < 4; ++i) {
                float v = acc[r][c][i] * scale + shift;
                v = v > 0.f ? v : 0.f;
                size_t off = (size_t)(row0 + i) * ystride + yoff + col;
                if (Yf) Yf[off] = v;
                else    Y[off] = (bf16)v;
            }
        }
    }
}

// ---------------------------------------------------------------------------
// z[:, 64:96] = sanitize(y2[align_idx])  (features_at_coordinates + concat)
// ---------------------------------------------------------------------------
__global__ void concat_kernel(const bf16* __restrict__ y2, const int* __restrict__ align,
                              bf16* __restrict__ z, int n) {
    int e = blockIdx.x * 256 + threadIdx.x;   // over n*32
    if (e >= n * 32) return;
    int i = e >> 5, c = e & 31;
    int a = align[i];
    float v = (float)y2[(size_t)a * 32 + c];
    unsigned u = __builtin_bit_cast(unsigned, v);
    if ((u & 0x7f800000u) == 0x7f800000u) v = 0.f;   // NaN/Inf -> 0
    z[(size_t)i * 96 + 64 + c] = (bf16)v;
}

// ---------------------------------------------------------------------------
extern "C" void kernel_launch(void* const* d_in, const int* in_sizes, int n_in,
                              void* d_out, int out_size, void* d_ws, size_t ws_size,
                              hipStream_t stream) {
    const float* feat3d = (const float*)d_in[0];
    const float* feat2d = (const float*)d_in[1];
    const float* Wsrc[11];
    for (int i = 0; i < 11; ++i) Wsrc[i] = (const float*)d_in[2 + i];
    const float* bn[22];
    for (int i = 0; i < 22; ++i) bn[i] = (const float*)d_in[13 + i];
    const int* nbr   = (const int*)d_in[35];
    const int* align = (const int*)d_in[36];
    float* out = (float*)d_out;

    const int n = in_sizes[0] / 96;   // 80000, divisible by 64

    // workspace layout
    char* ws = (char*)d_ws;
    size_t off = 0;
    auto alloc = [&](size_t bytes) -> void* {
        void* p = ws + off;
        off = (off + bytes + 255) & ~(size_t)255;
        return p;
    };
    bf16* F3 = (bf16*)alloc((size_t)n * 96 * 2);
    bf16* F2 = (bf16*)alloc((size_t)n * 256 * 2);
    static const int wt_taps[11] = {27, 1, 27, 1, 27, 1, 27, 1, 27, 1, 1};
    static const int wt_cin[11]  = {96, 64, 64, 64, 256, 64, 64, 32, 96, 128, 128};
    static const int wt_cout[11] = {64, 64, 64, 64, 64, 64, 32, 32, 128, 128, 128};
    bf16* Wf[11];
    for (int i = 0; i < 11; ++i)
        Wf[i] = (bf16*)alloc((size_t)wt_taps[i] * wt_cin[i] * wt_cout[i] * 2);
    bf16* tA = (bf16*)alloc((size_t)n * 64 * 2);
    bf16* tB = (bf16*)alloc((size_t)n * 64 * 2);
    bf16* y2 = (bf16*)alloc((size_t)n * 32 * 2);
    bf16* z  = (bf16*)alloc((size_t)n * 96 * 2);
    bf16* w1 = (bf16*)alloc((size_t)n * 128 * 2);
    bf16* w2 = (bf16*)alloc((size_t)n * 128 * 2);

    // ---- prep: converts + weight swizzles ----
    f2b_kernel<<<(n * 96 / 4 + 255) / 256, 256, 0, stream>>>(feat3d, F3, n * 96 / 4);
    f2b_kernel<<<(n * 256 / 4 + 255) / 256, 256, 0, stream>>>(feat2d, F2, n * 256 / 4);
    for (int i = 0; i < 11; ++i) {
        int total = wt_taps[i] * wt_cin[i] * wt_cout[i];
        swz_kernel<<<(total + 255) / 256, 256, 0, stream>>>(Wsrc[i], Wf[i], wt_cin[i], wt_cout[i], total);
    }

    const int GB = n / 64;   // 1250 blocks

    // ---- 3D branch: 96 -> 64 ----
    layer_kernel<96, 64, 27><<<GB, 256, 0, stream>>>(F3, Wf[0], nbr, bn[0], bn[1], tA, nullptr, 64, 0, n);
    layer_kernel<64, 64, 1 ><<<GB, 256, 0, stream>>>(tA, Wf[1], nullptr, bn[2], bn[3], tB, nullptr, 64, 0, n);
    layer_kernel<64, 64, 27><<<GB, 256, 0, stream>>>(tB, Wf[2], nbr, bn[4], bn[5], tA, nullptr, 64, 0, n);
    layer_kernel<64, 64, 1 ><<<GB, 256, 0, stream>>>(tA, Wf[3], nullptr, bn[6], bn[7], z, nullptr, 96, 0, n);   // x3 -> z[:,0:64]

    // ---- 2D branch: 256 -> 32 ----
    layer_kernel<256, 64, 27><<<GB, 256, 0, stream>>>(F2, Wf[4], nbr, bn[8], bn[9], tA, nullptr, 64, 0, n);
    layer_kernel<64, 64, 1  ><<<GB, 256, 0, stream>>>(tA, Wf[5], nullptr, bn[10], bn[11], tB, nullptr, 64, 0, n);
    layer_kernel<64, 32, 27 ><<<GB, 256, 0, stream>>>(tB, Wf[6], nbr, bn[12], bn[13], tA, nullptr, 32, 0, n);
    layer_kernel<32, 32, 1  ><<<GB, 256, 0, stream>>>(tA, Wf[7], nullptr, bn[14], bn[15], y2, nullptr, 32, 0, n);

    // ---- align gather + concat into z[:,64:96] ----
    concat_kernel<<<(n * 32 + 255) / 256, 256, 0, stream>>>(y2, align, z, n);

    // ---- fusion: 96 -> 128 -> 128 -> 128 ----
    layer_kernel<96, 128, 27><<<GB, 256, 0, stream>>>(z, Wf[8], nbr, bn[16], bn[17], w1, nullptr, 128, 0, n);
    layer_kernel<128, 128, 1><<<GB, 256, 0, stream>>>(w1, Wf[9], nullptr, bn[18], bn[19], w2, nullptr, 128, 0, n);
    layer_kernel<128, 128, 1><<<GB, 256, 0, stream>>>(w2, Wf[10], nullptr, bn[20], bn[21], nullptr, out, 128, 0, n);
}

// Round 3
// 645.473 us; speedup vs baseline: 1.5702x; 1.2825x over previous
//
#include <hip/hip_runtime.h>

typedef __bf16 bf16;
typedef __bf16 bf16x8 __attribute__((ext_vector_type(8)));
typedef __bf16 bf16x4 __attribute__((ext_vector_type(4)));
typedef float  f32x4  __attribute__((ext_vector_type(4)));

// ---------------------------------------------------------------------------
// f32 -> bf16 convert, 4-wide
// ---------------------------------------------------------------------------
__global__ void f2b_kernel(const float* __restrict__ src, bf16* __restrict__ dst, int n4) {
    int i = blockIdx.x * 256 + threadIdx.x;
    if (i >= n4) return;
    float4 v = ((const float4*)src)[i];
    bf16x4 o = { (bf16)v.x, (bf16)v.y, (bf16)v.z, (bf16)v.w };
    ((bf16x4*)dst)[i] = o;
}

// ---------------------------------------------------------------------------
// Swizzle fp32 W (taps, cin, cout) into bf16 MFMA-B-fragment order:
//   Wf[tap][s][nt][lane][j] = W[tap][s*32 + (lane>>4)*8 + j][nt*16 + (lane&15)]
// ---------------------------------------------------------------------------
__global__ void swz_kernel(const float* __restrict__ W, bf16* __restrict__ Wf,
                           int cin, int cout, int total) {
    int e = blockIdx.x * 256 + threadIdx.x;
    if (e >= total) return;
    int per_tap = cin * cout;
    int tap = e / per_tap;
    int t2  = e - tap * per_tap;
    int ntc = cout >> 4;               // number of 16-col tiles
    int s   = t2 / (ntc * 512);        // K-step of 32
    int r3  = t2 - s * (ntc * 512);
    int nt  = r3 >> 9;
    int L   = (r3 & 511) >> 3;
    int j   = r3 & 7;
    int k   = s * 32 + (L >> 4) * 8 + j;
    int col = nt * 16 + (L & 15);
    Wf[e] = (bf16)W[((size_t)tap * cin + k) * cout + col];
}

// ---------------------------------------------------------------------------
// One fused layer: Y = relu( (sum_k gather_k(X) @ W[k]) * sc + sh )
// Iteration space flattened over (K-half, tap); A staging split into
// issue-loads (before MFMA) and LDS-store (after MFMA) so gather latency
// overlaps compute within each wave. B-fragments straight global->VGPR,
// issued BEFORE the gather loads so vmcnt FIFO lets MFMA start early.
// ---------------------------------------------------------------------------
template<int CIN, int COUT, int TAPS, int KTILE>
__global__ __launch_bounds__(256) void layer_kernel(
    const bf16* __restrict__ X,
    const bf16* __restrict__ Wf,
    const int*  __restrict__ nbr,     // (TAPS, n) or nullptr when TAPS==1
    const float* __restrict__ sc, const float* __restrict__ sh,
    bf16* __restrict__ Y, float* __restrict__ Yf,
    int ystride, int yoff, int n)
{
    constexpr int NT   = COUT / 16;       // 16-col tiles
    constexpr int KH   = CIN / KTILE;     // K-passes
    constexpr int KS   = KTILE / 32;      // K-steps per iteration
    constexpr int CH   = KTILE / 8;       // 16B chunks per row
    constexpr int SREG = KTILE / 32;      // float4 staging regs per thread
    constexpr int AST  = KTILE + 8;       // padded LDS row stride
    constexpr int WR   = (COUT >= 64) ? 2 : 1;
    constexpr int WC   = (COUT == 128) ? 4 : 2;
    constexpr int RGRP = 4 / WR;
    constexpr int TOTAL = KH * TAPS;
    constexpr int NBUF = (TOTAL > 1) ? 2 : 1;
    constexpr int IDXN = (TAPS > 1) ? TAPS * 64 : 1;

    __shared__ __align__(16) bf16 As[NBUF][64 * AST];
    __shared__ int idxs[IDXN];

    const int tid  = threadIdx.x;
    const int base = blockIdx.x * 64;
    const int lane = tid & 63;
    const int wv   = tid >> 6;
    const int wrow = wv % RGRP;
    const int wcol = wv / RGRP;
    const int m16  = lane & 15;
    const int quad = lane >> 4;

    if (TAPS > 1) {
        for (int e = tid; e < TAPS * 64; e += 256)
            idxs[e] = nbr[(e >> 6) * n + base + (e & 63)];
        __syncthreads();
    }

    float4 sreg[SREG];
    auto issue_loads = [&](int it) {
        int kh = it / TAPS, t = it - kh * TAPS;
#pragma unroll
        for (int j = 0; j < SREG; ++j) {
            int e = tid + 256 * j;
            int r = e / CH, c = e - r * CH;
            int idx = (TAPS == 1) ? (base + r) : idxs[t * 64 + r];
            float4 val = {0.f, 0.f, 0.f, 0.f};
            if (idx >= 0) val = *(const float4*)(X + (size_t)idx * CIN + kh * KTILE + c * 8);
            sreg[j] = val;
        }
    };
    auto store_lds = [&](int buf) {
#pragma unroll
        for (int j = 0; j < SREG; ++j) {
            int e = tid + 256 * j;
            int r = e / CH, c = e - r * CH;
            *(float4*)(&As[buf][r * AST + c * 8]) = sreg[j];
        }
    };

    f32x4 acc[WR][WC];
#pragma unroll
    for (int r = 0; r < WR; ++r)
#pragma unroll
        for (int c = 0; c < WC; ++c) acc[r][c] = (f32x4){0.f, 0.f, 0.f, 0.f};

    issue_loads(0);
    store_lds(0);

    for (int it = 0; it < TOTAL; ++it) {
        __syncthreads();               // A(it) visible in buf it&1

        // B-fragments for this iteration (global, L2-hot) — issued first
        int kh = it / TAPS, t = it - kh * TAPS;
        const bf16* wt = Wf + (size_t)t * (CIN * COUT);
        bf16x8 b[KS][WC];
#pragma unroll
        for (int s = 0; s < KS; ++s)
#pragma unroll
            for (int c = 0; c < WC; ++c)
                b[s][c] = *(const bf16x8*)(wt + ((kh * KS + s) * NT + wcol * WC + c) * 512 + lane * 8);

        // gather loads for next iteration — stay in flight during MFMA
        if (it + 1 < TOTAL) issue_loads(it + 1);

        const int buf = it & (NBUF - 1);
#pragma unroll
        for (int s = 0; s < KS; ++s) {
            bf16x8 a[WR];
#pragma unroll
            for (int r = 0; r < WR; ++r) {
                int row = (wrow * WR + r) * 16 + m16;
                a[r] = *(const bf16x8*)(&As[buf][row * AST + s * 32 + quad * 8]);
            }
#pragma unroll
            for (int r = 0; r < WR; ++r)
#pragma unroll
                for (int c = 0; c < WC; ++c)
                    acc[r][c] = __builtin_amdgcn_mfma_f32_16x16x32_bf16(a[r], b[s][c], acc[r][c], 0, 0, 0);
        }

        if (it + 1 < TOTAL) store_lds((it + 1) & 1);   // waits vmcnt, writes other buf
    }

    // ---- epilogue: BN (folded) + ReLU; C/D layout col=lane&15, row=quad*4+i ----
#pragma unroll
    for (int c = 0; c < WC; ++c) {
        int col = (wcol * WC + c) * 16 + m16;
        float scale = sc[col], shift = sh[col];
#pragma unroll
        for (int r = 0; r < WR; ++r) {
            int row0 = base + (wrow * WR + r) * 16 + quad * 4;
#pragma unroll
            for (int i = 0; i < 4; ++i) {
                float v = acc[r][c][i] * scale + shift;
                v = v > 0.f ? v : 0.f;
                size_t off = (size_t)(row0 + i) * ystride + yoff + col;
                if (Yf) Yf[off] = v;
                else    Y[off] = (bf16)v;
            }
        }
    }
}

// ---------------------------------------------------------------------------
// z[:, 64:96] = sanitize(y2[align_idx])  (features_at_coordinates + concat)
// ---------------------------------------------------------------------------
__global__ void concat_kernel(const bf16* __restrict__ y2, const int* __restrict__ align,
                              bf16* __restrict__ z, int n) {
    int e = blockIdx.x * 256 + threadIdx.x;   // over n*32
    if (e >= n * 32) return;
    int i = e >> 5, c = e & 31;
    int a = align[i];
    float v = (float)y2[(size_t)a * 32 + c];
    unsigned u = __builtin_bit_cast(unsigned, v);
    if ((u & 0x7f800000u) == 0x7f800000u) v = 0.f;   // NaN/Inf -> 0
    z[(size_t)i * 96 + 64 + c] = (bf16)v;
}

// ---------------------------------------------------------------------------
extern "C" void kernel_launch(void* const* d_in, const int* in_sizes, int n_in,
                              void* d_out, int out_size, void* d_ws, size_t ws_size,
                              hipStream_t stream) {
    const float* feat3d = (const float*)d_in[0];
    const float* feat2d = (const float*)d_in[1];
    const float* Wsrc[11];
    for (int i = 0; i < 11; ++i) Wsrc[i] = (const float*)d_in[2 + i];
    const float* bn[22];
    for (int i = 0; i < 22; ++i) bn[i] = (const float*)d_in[13 + i];
    const int* nbr   = (const int*)d_in[35];
    const int* align = (const int*)d_in[36];
    float* out = (float*)d_out;

    const int n = in_sizes[0] / 96;   // 80000, divisible by 64

    // workspace layout
    char* ws = (char*)d_ws;
    size_t off = 0;
    auto alloc = [&](size_t bytes) -> void* {
        void* p = ws + off;
        off = (off + bytes + 255) & ~(size_t)255;
        return p;
    };
    bf16* F3 = (bf16*)alloc((size_t)n * 96 * 2);
    bf16* F2 = (bf16*)alloc((size_t)n * 256 * 2);
    static const int wt_taps[11] = {27, 1, 27, 1, 27, 1, 27, 1, 27, 1, 1};
    static const int wt_cin[11]  = {96, 64, 64, 64, 256, 64, 64, 32, 96, 128, 128};
    static const int wt_cout[11] = {64, 64, 64, 64, 64, 64, 32, 32, 128, 128, 128};
    bf16* Wf[11];
    for (int i = 0; i < 11; ++i)
        Wf[i] = (bf16*)alloc((size_t)wt_taps[i] * wt_cin[i] * wt_cout[i] * 2);
    bf16* tA = (bf16*)alloc((size_t)n * 64 * 2);
    bf16* tB = (bf16*)alloc((size_t)n * 64 * 2);
    bf16* y2 = (bf16*)alloc((size_t)n * 32 * 2);
    bf16* z  = (bf16*)alloc((size_t)n * 96 * 2);
    bf16* w1 = (bf16*)alloc((size_t)n * 128 * 2);
    bf16* w2 = (bf16*)alloc((size_t)n * 128 * 2);

    // ---- prep: converts + weight swizzles ----
    f2b_kernel<<<(n * 96 / 4 + 255) / 256, 256, 0, stream>>>(feat3d, F3, n * 96 / 4);
    f2b_kernel<<<(n * 256 / 4 + 255) / 256, 256, 0, stream>>>(feat2d, F2, n * 256 / 4);
    for (int i = 0; i < 11; ++i) {
        int total = wt_taps[i] * wt_cin[i] * wt_cout[i];
        swz_kernel<<<(total + 255) / 256, 256, 0, stream>>>(Wsrc[i], Wf[i], wt_cin[i], wt_cout[i], total);
    }

    const int GB = n / 64;   // 1250 blocks

    // ---- 3D branch: 96 -> 64 ----
    layer_kernel<96, 64, 27, 96><<<GB, 256, 0, stream>>>(F3, Wf[0], nbr, bn[0], bn[1], tA, nullptr, 64, 0, n);
    layer_kernel<64, 64, 1, 64 ><<<GB, 256, 0, stream>>>(tA, Wf[1], nullptr, bn[2], bn[3], tB, nullptr, 64, 0, n);
    layer_kernel<64, 64, 27, 64><<<GB, 256, 0, stream>>>(tB, Wf[2], nbr, bn[4], bn[5], tA, nullptr, 64, 0, n);
    layer_kernel<64, 64, 1, 64 ><<<GB, 256, 0, stream>>>(tA, Wf[3], nullptr, bn[6], bn[7], z, nullptr, 96, 0, n);   // x3 -> z[:,0:64]

    // ---- 2D branch: 256 -> 32 ----
    layer_kernel<256, 64, 27, 128><<<GB, 256, 0, stream>>>(F2, Wf[4], nbr, bn[8], bn[9], tA, nullptr, 64, 0, n);
    layer_kernel<64, 64, 1, 64   ><<<GB, 256, 0, stream>>>(tA, Wf[5], nullptr, bn[10], bn[11], tB, nullptr, 64, 0, n);
    layer_kernel<64, 32, 27, 64  ><<<GB, 256, 0, stream>>>(tB, Wf[6], nbr, bn[12], bn[13], tA, nullptr, 32, 0, n);
    layer_kernel<32, 32, 1, 32   ><<<GB, 256, 0, stream>>>(tA, Wf[7], nullptr, bn[14], bn[15], y2, nullptr, 32, 0, n);

    // ---- align gather + concat into z[:,64:96] ----
    concat_kernel<<<(n * 32 + 255) / 256, 256, 0, stream>>>(y2, align, z, n);

    // ---- fusion: 96 -> 128 -> 128 -> 128 ----
    layer_kernel<96, 128, 27, 96><<<GB, 256, 0, stream>>>(z, Wf[8], nbr, bn[16], bn[17], w1, nullptr, 128, 0, n);
    layer_kernel<128, 128, 1, 128><<<GB, 256, 0, stream>>>(w1, Wf[9], nullptr, bn[18], bn[19], w2, nullptr, 128, 0, n);
    layer_kernel<128, 128, 1, 128><<<GB, 256, 0, stream>>>(w2, Wf[10], nullptr, bn[20], bn[21], nullptr, out, 128, 0, n);
}

// Round 4
// 593.910 us; speedup vs baseline: 1.7065x; 1.0868x over previous
//
#include <hip/hip_runtime.h>

typedef __bf16 bf16;
typedef __bf16 bf16x8 __attribute__((ext_vector_type(8)));
typedef __bf16 bf16x4 __attribute__((ext_vector_type(4)));
typedef float  f32x4  __attribute__((ext_vector_type(4)));

// ---------------------------------------------------------------------------
// f32 -> bf16 convert, 4-wide
// ---------------------------------------------------------------------------
__global__ void f2b_kernel(const float* __restrict__ src, bf16* __restrict__ dst, int n4) {
    int i = blockIdx.x * 256 + threadIdx.x;
    if (i >= n4) return;
    float4 v = ((const float4*)src)[i];
    bf16x4 o = { (bf16)v.x, (bf16)v.y, (bf16)v.z, (bf16)v.w };
    ((bf16x4*)dst)[i] = o;
}

// ---------------------------------------------------------------------------
// Swizzle fp32 W (taps, cin, cout) into bf16 MFMA-B-fragment order:
//   Wf[tap][s][nt][lane][j] = W[tap][s*32 + (lane>>4)*8 + j][nt*16 + (lane&15)]
// ---------------------------------------------------------------------------
__global__ void swz_kernel(const float* __restrict__ W, bf16* __restrict__ Wf,
                           int cin, int cout, int total) {
    int e = blockIdx.x * 256 + threadIdx.x;
    if (e >= total) return;
    int per_tap = cin * cout;
    int tap = e / per_tap;
    int t2  = e - tap * per_tap;
    int ntc = cout >> 4;               // number of 16-col tiles
    int s   = t2 / (ntc * 512);        // K-step of 32
    int r3  = t2 - s * (ntc * 512);
    int nt  = r3 >> 9;
    int L   = (r3 & 511) >> 3;
    int j   = r3 & 7;
    int k   = s * 32 + (L >> 4) * 8 + j;
    int col = nt * 16 + (L & 15);
    Wf[e] = (bf16)W[((size_t)tap * cin + k) * cout + col];
}

// ---------------------------------------------------------------------------
// Fused layer chain:
//   h1 = relu( (sum_t gather_t(X) @ W1[t]) * sc1 + sh1 )      (sparse conv)
//   h2 = relu( (h1 @ W2) * sc2 + sh2 )                        (fused dense)
//   h3 = relu( (h2 @ W3) * sc3 + sh3 )                        (optional 2nd dense)
// Sparse part: software-pipelined gather->LDS with 1 barrier/tap; B-frags
// straight global->VGPR. Dense parts: relu'd tile round-trips through LDS
// (aliasing the A buffers) then standard MFMA passes.
// Block ids are swizzled so each XCD gets a CONTIGUOUS chunk of row-space:
// consecutive blocks share gather neighbors -> per-XCD L2 working set ~1 MB.
// ---------------------------------------------------------------------------
template<int CIN, int C1, int TAPS, int KTILE, int C2, int C3>
__global__ __launch_bounds__(256) void layer_kernel(
    const bf16* __restrict__ X,
    const bf16* __restrict__ W1,     // swizzled (TAPS, CIN, C1)
    const bf16* __restrict__ W2,     // swizzled (C1, C2)
    const bf16* __restrict__ W3,     // swizzled (C2, C3) or null
    const int*  __restrict__ nbr,    // (TAPS, n)
    const float* __restrict__ sc1, const float* __restrict__ sh1,
    const float* __restrict__ sc2, const float* __restrict__ sh2,
    const float* __restrict__ sc3, const float* __restrict__ sh3,
    bf16* __restrict__ Y, float* __restrict__ Yf,
    int ystride, int yoff, int n, int nblocks)
{
    constexpr int NT1  = C1 / 16;
    constexpr int KH   = CIN / KTILE;
    constexpr int KS   = KTILE / 32;
    constexpr int CH   = KTILE / 8;      // 16B chunks per staged row
    constexpr int SREG = KTILE / 32;     // float4 staging regs per thread
    constexpr int AST  = KTILE + 8;
    constexpr int WR1  = (C1 >= 64) ? 2 : 1;
    constexpr int WC1  = (C1 == 128) ? 4 : 2;
    constexpr int RG1  = 4 / WR1;
    constexpr int ABUF = 64 * AST;       // elements per A buffer
    constexpr int ABY  = 2 * ABUF * 2;
    constexpr int LS1  = C1 + 8;
    constexpr int LS2  = C2 + 8;
    constexpr int L1BY = 64 * LS1 * 2;
    constexpr int L2BY = (C3 > 0) ? 64 * LS2 * 2 : 0;
    constexpr int SBY  = (ABY > L1BY ? (ABY > L2BY ? ABY : L2BY)
                                     : (L1BY > L2BY ? L1BY : L2BY));

    __shared__ __align__(16) char smem[SBY];
    __shared__ int idxs[TAPS * 64];
    bf16* As = (bf16*)smem;

    const int tid = threadIdx.x;

    // XCD-contiguous block swizzle (bijection; perf-only assumption b%8->XCD)
    {
    }
    const int bq  = nblocks >> 3, br = nblocks & 7;
    const int bx  = blockIdx.x & 7, bs = blockIdx.x >> 3;
    const int sb  = bx * bq + (bx < br ? bx : br) + bs;
    const int base = sb * 64;

    const int lane  = tid & 63;
    const int wv    = tid >> 6;
    const int m16   = lane & 15;
    const int quad  = lane >> 4;
    const int wrow1 = wv % RG1;
    const int wcol1 = wv / RG1;

    for (int e = tid; e < TAPS * 64; e += 256)
        idxs[e] = nbr[(e >> 6) * n + base + (e & 63)];
    __syncthreads();

    // loop-invariant staging geometry
    int rr[SREG], cof[SREG], lofs[SREG];
#pragma unroll
    for (int j = 0; j < SREG; ++j) {
        int e = tid + 256 * j;
        rr[j]   = e / CH;
        int c   = e - rr[j] * CH;
        cof[j]  = c * 8;
        lofs[j] = rr[j] * AST + c * 8;
    }

    float4 sreg[SREG];
    auto issue_loads = [&](int kh, int t) {
#pragma unroll
        for (int j = 0; j < SREG; ++j) {
            int idx = idxs[t * 64 + rr[j]];
            float4 val = {0.f, 0.f, 0.f, 0.f};
            if (idx >= 0) val = *(const float4*)(X + (size_t)idx * CIN + kh * KTILE + cof[j]);
            sreg[j] = val;
        }
    };
    auto store_lds = [&](int buf) {
#pragma unroll
        for (int j = 0; j < SREG; ++j)
            *(float4*)(&As[buf * ABUF + lofs[j]]) = sreg[j];
    };

    f32x4 acc1[WR1][WC1];
#pragma unroll
    for (int r = 0; r < WR1; ++r)
#pragma unroll
        for (int c = 0; c < WC1; ++c) acc1[r][c] = (f32x4){0.f, 0.f, 0.f, 0.f};

    issue_loads(0, 0);
    store_lds(0);

    int it = 0;
    for (int kh = 0; kh < KH; ++kh)
        for (int t = 0; t < TAPS; ++t, ++it) {
            __syncthreads();                       // A(it) visible

            const bf16* wt = W1 + (size_t)t * (CIN * C1);
            bf16x8 bfr[KS][WC1];
#pragma unroll
            for (int s = 0; s < KS; ++s)
#pragma unroll
                for (int c = 0; c < WC1; ++c)
                    bfr[s][c] = *(const bf16x8*)(wt + ((kh * KS + s) * NT1 + wcol1 * WC1 + c) * 512 + lane * 8);

            int t2 = t + 1, kh2 = kh;
            if (t2 == TAPS) { t2 = 0; kh2 = kh + 1; }
            const bool more = (kh2 < KH);
            if (more) issue_loads(kh2, t2);        // in flight during MFMA

            const int buf = it & 1;
#pragma unroll
            for (int s = 0; s < KS; ++s) {
                bf16x8 a[WR1];
#pragma unroll
                for (int r = 0; r < WR1; ++r)
                    a[r] = *(const bf16x8*)(&As[buf * ABUF + ((wrow1 * WR1 + r) * 16 + m16) * AST + s * 32 + quad * 8]);
#pragma unroll
                for (int r = 0; r < WR1; ++r)
#pragma unroll
                    for (int c = 0; c < WC1; ++c)
                        acc1[r][c] = __builtin_amdgcn_mfma_f32_16x16x32_bf16(a[r], bfr[s][c], acc1[r][c], 0, 0, 0);
            }

            if (more) store_lds(buf ^ 1);
        }

    // ---- stage-1 epilogue -> LDS tile (bf16) ----
    __syncthreads();                               // all As reads done
    bf16* Lt1 = (bf16*)smem;
#pragma unroll
    for (int c = 0; c < WC1; ++c) {
        int col = (wcol1 * WC1 + c) * 16 + m16;
        float s1 = sc1[col], h1 = sh1[col];
#pragma unroll
        for (int r = 0; r < WR1; ++r) {
            int row0 = (wrow1 * WR1 + r) * 16 + quad * 4;
#pragma unroll
            for (int i = 0; i < 4; ++i) {
                float v = acc1[r][c][i] * s1 + h1;
                v = v > 0.f ? v : 0.f;
                Lt1[(row0 + i) * LS1 + col] = (bf16)v;
            }
        }
    }
    __syncthreads();

    // ---- stage 2: dense GEMM K=C1 ----
    constexpr int NT2 = C2 / 16;
    constexpr int WR2 = (C2 >= 64) ? 2 : 1;
    constexpr int WC2 = (C2 == 128) ? 4 : 2;
    constexpr int RG2 = 4 / WR2;
    constexpr int KS2 = C1 / 32;
    const int wrow2 = wv % RG2, wcol2 = wv / RG2;

    f32x4 acc2[WR2][WC2];
#pragma unroll
    for (int r = 0; r < WR2; ++r)
#pragma unroll
        for (int c = 0; c < WC2; ++c) acc2[r][c] = (f32x4){0.f, 0.f, 0.f, 0.f};

#pragma unroll
    for (int s = 0; s < KS2; ++s) {
        bf16x8 a[WR2], bw[WC2];
#pragma unroll
        for (int r = 0; r < WR2; ++r)
            a[r] = *(const bf16x8*)(&Lt1[((wrow2 * WR2 + r) * 16 + m16) * LS1 + s * 32 + quad * 8]);
#pragma unroll
        for (int c = 0; c < WC2; ++c)
            bw[c] = *(const bf16x8*)(W2 + ((s * NT2 + wcol2 * WC2 + c) * 512 + lane * 8));
#pragma unroll
        for (int r = 0; r < WR2; ++r)
#pragma unroll
            for (int c = 0; c < WC2; ++c)
                acc2[r][c] = __builtin_amdgcn_mfma_f32_16x16x32_bf16(a[r], bw[c], acc2[r][c], 0, 0, 0);
    }

    if constexpr (C3 == 0) {
        // ---- final epilogue from acc2 ----
#pragma unroll
        for (int c = 0; c < WC2; ++c) {
            int col = (wcol2 * WC2 + c) * 16 + m16;
            float s2 = sc2[col], h2 = sh2[col];
#pragma unroll
            for (int r = 0; r < WR2; ++r) {
                int row0 = base + (wrow2 * WR2 + r) * 16 + quad * 4;
#pragma unroll
                for (int i = 0; i < 4; ++i) {
                    float v = acc2[r][c][i] * s2 + h2;
                    v = v > 0.f ? v : 0.f;
                    size_t off = (size_t)(row0 + i) * ystride + yoff + col;
                    if (Yf) Yf[off] = v;
                    else    Y[off] = (bf16)v;
                }
            }
        }
    } else {
        // ---- stage-2 epilogue -> LDS, then stage 3 ----
        __syncthreads();                           // Lt1 reads done
        bf16* Lt2 = (bf16*)smem;
#pragma unroll
        for (int c = 0; c < WC2; ++c) {
            int col = (wcol2 * WC2 + c) * 16 + m16;
            float s2 = sc2[col], h2 = sh2[col];
#pragma unroll
            for (int r = 0; r < WR2; ++r) {
                int row0 = (wrow2 * WR2 + r) * 16 + quad * 4;
#pragma unroll
                for (int i = 0; i < 4; ++i) {
                    float v = acc2[r][c][i] * s2 + h2;
                    v = v > 0.f ? v : 0.f;
                    Lt2[(row0 + i) * LS2 + col] = (bf16)v;
                }
            }
        }
        __syncthreads();

        constexpr int C3v = (C3 > 0) ? C3 : 16;    // avoid div-by-zero in dead code
        constexpr int NT3 = C3v / 16;
        constexpr int WR3 = (C3v >= 64) ? 2 : 1;
        constexpr int WC3 = (C3v == 128) ? 4 : 2;
        constexpr int RG3 = 4 / WR3;
        constexpr int KS3 = C2 / 32;
        const int wrow3 = wv % RG3, wcol3 = wv / RG3;

        f32x4 acc3[WR3][WC3];
#pragma unroll
        for (int r = 0; r < WR3; ++r)
#pragma unroll
            for (int c = 0; c < WC3; ++c) acc3[r][c] = (f32x4){0.f, 0.f, 0.f, 0.f};

#pragma unroll
        for (int s = 0; s < KS3; ++s) {
            bf16x8 a[WR3], bw[WC3];
#pragma unroll
            for (int r = 0; r < WR3; ++r)
                a[r] = *(const bf16x8*)(&Lt2[((wrow3 * WR3 + r) * 16 + m16) * LS2 + s * 32 + quad * 8]);
#pragma unroll
            for (int c = 0; c < WC3; ++c)
                bw[c] = *(const bf16x8*)(W3 + ((s * NT3 + wcol3 * WC3 + c) * 512 + lane * 8));
#pragma unroll
            for (int r = 0; r < WR3; ++r)
#pragma unroll
                for (int c = 0; c < WC3; ++c)
                    acc3[r][c] = __builtin_amdgcn_mfma_f32_16x16x32_bf16(a[r], bw[c], acc3[r][c], 0, 0, 0);
        }

#pragma unroll
        for (int c = 0; c < WC3; ++c) {
            int col = (wcol3 * WC3 + c) * 16 + m16;
            float s3 = sc3[col], h3 = sh3[col];
#pragma unroll
            for (int r = 0; r < WR3; ++r) {
                int row0 = base + (wrow3 * WR3 + r) * 16 + quad * 4;
#pragma unroll
                for (int i = 0; i < 4; ++i) {
                    float v = acc3[r][c][i] * s3 + h3;
                    v = v > 0.f ? v : 0.f;
                    size_t off = (size_t)(row0 + i) * ystride + yoff + col;
                    if (Yf) Yf[off] = v;
                    else    Y[off] = (bf16)v;
                }
            }
        }
    }
}

// ---------------------------------------------------------------------------
// z[:, 64:96] = sanitize(y2[align_idx])  (features_at_coordinates + concat)
// ---------------------------------------------------------------------------
__global__ void concat_kernel(const bf16* __restrict__ y2, const int* __restrict__ align,
                              bf16* __restrict__ z, int n) {
    int e = blockIdx.x * 256 + threadIdx.x;   // over n*32
    if (e >= n * 32) return;
    int i = e >> 5, c = e & 31;
    int a = align[i];
    float v = (float)y2[(size_t)a * 32 + c];
    unsigned u = __builtin_bit_cast(unsigned, v);
    if ((u & 0x7f800000u) == 0x7f800000u) v = 0.f;   // NaN/Inf -> 0
    z[(size_t)i * 96 + 64 + c] = (bf16)v;
}

// ---------------------------------------------------------------------------
extern "C" void kernel_launch(void* const* d_in, const int* in_sizes, int n_in,
                              void* d_out, int out_size, void* d_ws, size_t ws_size,
                              hipStream_t stream) {
    const float* feat3d = (const float*)d_in[0];
    const float* feat2d = (const float*)d_in[1];
    const float* Wsrc[11];
    for (int i = 0; i < 11; ++i) Wsrc[i] = (const float*)d_in[2 + i];
    const float* bn[22];
    for (int i = 0; i < 22; ++i) bn[i] = (const float*)d_in[13 + i];
    const int* nbr   = (const int*)d_in[35];
    const int* align = (const int*)d_in[36];
    float* out = (float*)d_out;

    const int n = in_sizes[0] / 96;   // 80000, divisible by 64

    // workspace layout
    char* ws = (char*)d_ws;
    size_t off = 0;
    auto alloc = [&](size_t bytes) -> void* {
        void* p = ws + off;
        off = (off + bytes + 255) & ~(size_t)255;
        return p;
    };
    bf16* F3 = (bf16*)alloc((size_t)n * 96 * 2);
    bf16* F2 = (bf16*)alloc((size_t)n * 256 * 2);
    static const int wt_taps[11] = {27, 1, 27, 1, 27, 1, 27, 1, 27, 1, 1};
    static const int wt_cin[11]  = {96, 64, 64, 64, 256, 64, 64, 32, 96, 128, 128};
    static const int wt_cout[11] = {64, 64, 64, 64, 64, 64, 32, 32, 128, 128, 128};
    bf16* Wf[11];
    for (int i = 0; i < 11; ++i)
        Wf[i] = (bf16*)alloc((size_t)wt_taps[i] * wt_cin[i] * wt_cout[i] * 2);
    bf16* tA = (bf16*)alloc((size_t)n * 64 * 2);
    bf16* tB = (bf16*)alloc((size_t)n * 64 * 2);
    bf16* y2 = (bf16*)alloc((size_t)n * 32 * 2);
    bf16* z  = (bf16*)alloc((size_t)n * 96 * 2);

    // ---- prep: converts + weight swizzles ----
    f2b_kernel<<<(n * 96 / 4 + 255) / 256, 256, 0, stream>>>(feat3d, F3, n * 96 / 4);
    f2b_kernel<<<(n * 256 / 4 + 255) / 256, 256, 0, stream>>>(feat2d, F2, n * 256 / 4);
    for (int i = 0; i < 11; ++i) {
        int total = wt_taps[i] * wt_cin[i] * wt_cout[i];
        swz_kernel<<<(total + 255) / 256, 256, 0, stream>>>(Wsrc[i], Wf[i], wt_cin[i], wt_cout[i], total);
    }

    const int GB = n / 64;   // 1250 blocks

    // ---- 3D branch: (a1+a2), (a3+a4) ----
    layer_kernel<96, 64, 27, 96, 64, 0><<<GB, 256, 0, stream>>>(
        F3, Wf[0], Wf[1], nullptr, nbr,
        bn[0], bn[1], bn[2], bn[3], nullptr, nullptr,
        tB, nullptr, 64, 0, n, GB);
    layer_kernel<64, 64, 27, 64, 64, 0><<<GB, 256, 0, stream>>>(
        tB, Wf[2], Wf[3], nullptr, nbr,
        bn[4], bn[5], bn[6], bn[7], nullptr, nullptr,
        z, nullptr, 96, 0, n, GB);                 // x3 -> z[:,0:64]

    // ---- 2D branch: (b1+b2), (b3+b4) ----
    layer_kernel<256, 64, 27, 128, 64, 0><<<GB, 256, 0, stream>>>(
        F2, Wf[4], Wf[5], nullptr, nbr,
        bn[8], bn[9], bn[10], bn[11], nullptr, nullptr,
        tA, nullptr, 64, 0, n, GB);
    layer_kernel<64, 32, 27, 64, 32, 0><<<GB, 256, 0, stream>>>(
        tA, Wf[6], Wf[7], nullptr, nbr,
        bn[12], bn[13], bn[14], bn[15], nullptr, nullptr,
        y2, nullptr, 32, 0, n, GB);

    // ---- align gather + concat into z[:,64:96] ----
    concat_kernel<<<(n * 32 + 255) / 256, 256, 0, stream>>>(y2, align, z, n);

    // ---- fusion: (c1+c2+c3) ----
    layer_kernel<96, 128, 27, 96, 128, 128><<<GB, 256, 0, stream>>>(
        z, Wf[8], Wf[9], Wf[10], nbr,
        bn[16], bn[17], bn[18], bn[19], bn[20], bn[21],
        nullptr, out, 128, 0, n, GB);
}